// Round 10
// baseline (282.024 us; speedup 1.0000x reference)
//
#include <hip/hip_runtime.h>

#define N_NODES 50000
#define N_EDGES 600000
#define DFEAT   128
#define NTILES  (N_NODES / 16)             // 3125 tiles of 16 rows (exact)
#define DEGCAP  64                         // max degree slots (Poisson(12) max ~35)

typedef __attribute__((ext_vector_type(8))) short short8;
typedef __attribute__((ext_vector_type(4))) float floatx4;

__device__ __forceinline__ unsigned short f2bf_rtne(float f) {
    unsigned b = __float_as_uint(f);
    return (unsigned short)((b + 0x7FFFu + ((b >> 16) & 1u)) >> 16);
}
__device__ __forceinline__ float bf2f(unsigned short u) {
    return __uint_as_float(((unsigned)u) << 16);
}
// LDS index swizzle: rows x 256 ushorts. XOR bits 3..5 of col with row&7:
// all accesses are >=4-ushort aligned and stay inside one 8-ushort block,
// so write/read mappings agree. Validated R5/R7 (passed, absmax 0.015625).
__device__ __forceinline__ int ldsx(int row, int col) {
    return row * 256 + (col ^ ((row & 7) << 3));
}

// ========== fused build: bucket-fill (cnt pre-zeroed by memset) + prep =========
__global__ __launch_bounds__(256) void sage_build_kernel(
        const float* __restrict__ x, const int* __restrict__ src, const int* __restrict__ dst,
        const float* __restrict__ Ws0, const float* __restrict__ Wn0,
        const float* __restrict__ Ws1, const float* __restrict__ Wn1,
        const float* __restrict__ Ws2, const float* __restrict__ Wn2,
        unsigned short* __restrict__ Whi0, unsigned short* __restrict__ Wlo0,
        unsigned short* __restrict__ Whi1, unsigned short* __restrict__ Wlo1,
        unsigned short* __restrict__ Whi2, unsigned short* __restrict__ Wlo2,
        unsigned short* __restrict__ hb, int* __restrict__ cnt,
        unsigned short* __restrict__ ssrc)
{
    const int gtid = blockIdx.x * 256 + threadIdx.x;
    const int gsz  = gridDim.x * 256;

    // ---- bucket fill (latency/atomic-bound; overlaps prep's streaming) ----
    for (int e = gtid; e < N_EDGES; e += gsz) {
        int d = dst[e];
        int p = atomicAdd(&cnt[d], 1);
        if (p < DEGCAP) ssrc[(d << 6) + p] = (unsigned short)src[e];
    }

    // ---- x -> bf16 table ----
    for (int i = gtid; i < N_NODES * DFEAT / 4; i += gsz) {
        float4 v = ((const float4*)x)[i];
        ushort4 o;
        o.x = f2bf_rtne(v.x); o.y = f2bf_rtne(v.y);
        o.z = f2bf_rtne(v.z); o.w = f2bf_rtne(v.w);
        ((ushort4*)hb)[i] = o;
    }

    // ---- W split/swizzle into MFMA fragment order ----
    for (int it = gtid; it < 160 * 64; it += gsz) {
        int fid_g = it >> 6;
        int lane  = it & 63;
        const float *Ws, *Wn;
        unsigned short *Whi, *Wlo;
        int N, fid;
        if (fid_g < 64)       { Ws = Ws0; Wn = Wn0; Whi = Whi0; Wlo = Wlo0; N = 128; fid = fid_g; }
        else if (fid_g < 128) { Ws = Ws1; Wn = Wn1; Whi = Whi1; Wlo = Wlo1; N = 128; fid = fid_g - 64; }
        else                  { Ws = Ws2; Wn = Wn2; Whi = Whi2; Wlo = Wlo2; N = 64;  fid = fid_g - 128; }
        int NT = N / 16;
        int kt = fid / NT, nt = fid % NT;
        int kbase = kt * 32 + (lane >> 4) * 8;
        int n = nt * 16 + (lane & 15);
        long base = ((long)fid * 64 + lane) * 8;
        #pragma unroll
        for (int j = 0; j < 8; j++) {
            int k = kbase + j;
            float w = (k < 128) ? Ws[k * N + n] : Wn[(k - 128) * N + n];
            unsigned bb = __float_as_uint(w);
            unsigned hib = bb & 0xFFFF0000u;
            float lo = w - __uint_as_float(hib);
            Whi[base + j] = (unsigned short)(bb >> 16);
            Wlo[base + j] = (unsigned short)(__float_as_uint(lo) >> 16);
        }
    }
}

// ================= FUSED layer: gather-mean + dual bf16 MFMA matmul =============
// NEW SHAPE: block = 128 threads (2 waves) owns 16 output rows; grid = 3125
// (= 50000/16 exactly, so NO bounds checks anywhere). 12.2 blocks/CU
// co-resident (~24 waves/CU vs 16 before) + finer tail granularity.
// Phase A1: stage 16 self rows into LDS (coalesced 16B chunks).
// Phase A2: gather 16 mean rows (R7-proven paired-edge: lanes 0-31 even
//           edges, 32-63 odd; each lane ushort4 = 8B; combine shfl_down(32)).
// Phase B:  2 waves split N columns (NT/2 n-tiles each); A-frags from LDS
//           (XOR-swizzled rows), B-frags (hi/lo split W) from L2.
template<int NT, bool RELU, bool FINAL>
__global__ __launch_bounds__(128) void sage_layer_kernel(
        const unsigned short* __restrict__ hb, const int* __restrict__ cnt,
        const unsigned short* __restrict__ ssrc,
        const unsigned short* __restrict__ Whi, const unsigned short* __restrict__ Wlo,
        const float* __restrict__ bias, float* __restrict__ out,
        unsigned short* __restrict__ hb_out)
{
    constexpr int N   = NT * 16;
    constexpr int NTW = NT / 2;          // n-tiles per wave
    __shared__ __align__(16) unsigned short lds[16 * 256];   // 8192 B

    const int tid  = threadIdx.x;
    const int w    = tid >> 6;           // 0..1
    const int lane = tid & 63;
    const int rowbase = blockIdx.x * 16;

    // ---- phase A1: stage self rows (coalesced 16B chunks, no bounds) ----
    #pragma unroll
    for (int i = 0; i < 2; i++) {
        int idx = tid + i * 128;               // 0..255 chunks of 16B
        int r = idx >> 4, o = idx & 15;
        short8 v = *(const short8*)(hb + (((long)(rowbase + r)) << 7) + o * 8);
        *(short8*)(&lds[ldsx(r, o * 8)]) = v;
    }

    // ---- phase A2: gather means (paired-edge, 2 rows in flight per half) ----
    const int half = lane >> 5;
    const int fq   = lane & 31;                // feature quad: feats fq*4..+3
    for (int n = 0; n < 8; n++) {
        const int node = rowbase + w * 8 + n;  // wave-uniform, always < N_NODES
        const int deg = cnt[node];
        const int beg = node << 6;
        const int end = beg + (deg < DEGCAP ? deg : DEGCAP);
        float4 s0 = make_float4(0.f, 0.f, 0.f, 0.f);
        float4 s1 = make_float4(0.f, 0.f, 0.f, 0.f);
        int e = beg + half;
        for (; e + 2 < end; e += 4) {
            int sA = ssrc[e];
            int sB = ssrc[e + 2];
            ushort4 vA = *(const ushort4*)(hb + ((long)sA << 7) + fq * 4);
            ushort4 vB = *(const ushort4*)(hb + ((long)sB << 7) + fq * 4);
            s0.x += bf2f(vA.x); s0.y += bf2f(vA.y); s0.z += bf2f(vA.z); s0.w += bf2f(vA.w);
            s1.x += bf2f(vB.x); s1.y += bf2f(vB.y); s1.z += bf2f(vB.z); s1.w += bf2f(vB.w);
        }
        for (; e < end; e += 2) {
            int sA = ssrc[e];
            ushort4 vA = *(const ushort4*)(hb + ((long)sA << 7) + fq * 4);
            s0.x += bf2f(vA.x); s0.y += bf2f(vA.y); s0.z += bf2f(vA.z); s0.w += bf2f(vA.w);
        }
        float sx = s0.x + s1.x, sy = s0.y + s1.y, sz = s0.z + s1.z, sw = s0.w + s1.w;
        sx += __shfl_down(sx, 32);
        sy += __shfl_down(sy, 32);
        sz += __shfl_down(sz, 32);
        sw += __shfl_down(sw, 32);
        if (half == 0) {
            float sc = 1.0f / fmaxf((float)deg, 1.0f);
            ushort4 r;
            r.x = f2bf_rtne(sx * sc); r.y = f2bf_rtne(sy * sc);
            r.z = f2bf_rtne(sz * sc); r.w = f2bf_rtne(sw * sc);
            *(ushort4*)(&lds[ldsx(w * 8 + n, 128 + fq * 4)]) = r;
        }
    }
    __syncthreads();

    // ---- phase B: dual matmul (self kt 0..3 | mean kt 4..7) ----
    const int q   = lane >> 4;
    const int l16 = lane & 15;

    floatx4 acc[NTW];
    #pragma unroll
    for (int ntl = 0; ntl < NTW; ntl++)
        acc[ntl] = (floatx4){0.f, 0.f, 0.f, 0.f};

    #pragma unroll
    for (int kt = 0; kt < 8; kt++) {
        short8 am = *(const short8*)(&lds[ldsx(l16, kt * 32 + q * 8)]);
        #pragma unroll
        for (int ntl = 0; ntl < NTW; ntl++) {
            int nt = w * NTW + ntl;
            long fb = ((long)(kt * NT + nt) * 64 + lane) * 8;
            short8 bhi = *(const short8*)(Whi + fb);
            short8 blo = *(const short8*)(Wlo + fb);
            acc[ntl] = __builtin_amdgcn_mfma_f32_16x16x32_bf16(am, bhi, acc[ntl], 0, 0, 0);
            acc[ntl] = __builtin_amdgcn_mfma_f32_16x16x32_bf16(am, blo, acc[ntl], 0, 0, 0);
        }
    }

    #pragma unroll
    for (int ntl = 0; ntl < NTW; ntl++) {
        int col = (w * NTW + ntl) * 16 + l16;
        float bv = bias[col];
        #pragma unroll
        for (int reg = 0; reg < 4; reg++) {
            int grow = rowbase + q * 4 + reg;
            float v = acc[ntl][reg] + bv;
            if (RELU) v = fmaxf(v, 0.f);
            long idx = (long)grow * N + col;
            if (FINAL) out[idx] = v;
            else       hb_out[idx] = f2bf_rtne(v);
        }
    }
}

extern "C" void kernel_launch(void* const* d_in, const int* in_sizes, int n_in,
                              void* d_out, int out_size, void* d_ws, size_t ws_size,
                              hipStream_t stream) {
    const float* x   = (const float*)d_in[0];
    const int*   ei  = (const int*)d_in[1];
    const float* Ws0 = (const float*)d_in[2];
    const float* Wn0 = (const float*)d_in[3];
    const float* b0  = (const float*)d_in[4];
    const float* Ws1 = (const float*)d_in[5];
    const float* Wn1 = (const float*)d_in[6];
    const float* b1  = (const float*)d_in[7];
    const float* Ws2 = (const float*)d_in[8];
    const float* Wn2 = (const float*)d_in[9];
    const float* b2  = (const float*)d_in[10];
    float* out = (float*)d_out;

    const int* src = ei;
    const int* dst = ei + N_EDGES;

    // ---- workspace layout ----
    char* ws = (char*)d_ws;
    int*   cnt        = (int*)ws;     ws += 50176 * 4;
    unsigned short* ssrc = (unsigned short*)ws; ws += (long)N_NODES * DEGCAP * 2; // 6.4 MB
    unsigned short* Whi0 = (unsigned short*)ws; ws += 8 * 8 * 64 * 8 * 2;   // 64 KB
    unsigned short* Wlo0 = (unsigned short*)ws; ws += 8 * 8 * 64 * 8 * 2;
    unsigned short* Whi1 = (unsigned short*)ws; ws += 8 * 8 * 64 * 8 * 2;
    unsigned short* Wlo1 = (unsigned short*)ws; ws += 8 * 8 * 64 * 8 * 2;
    unsigned short* Whi2 = (unsigned short*)ws; ws += 8 * 4 * 64 * 8 * 2;   // 32 KB
    unsigned short* Wlo2 = (unsigned short*)ws; ws += 8 * 4 * 64 * 8 * 2;
    unsigned short* hb_a = (unsigned short*)ws; ws += (long)N_NODES * DFEAT * 2; // 12.8 MB
    unsigned short* hb_b = (unsigned short*)ws; ws += (long)N_NODES * DFEAT * 2; // 12.8 MB

    // ---- build: memset(cnt) + fused fill/prep (2 enqueues) ----
    hipMemsetAsync(cnt, 0, 50176 * 4, stream);
    sage_build_kernel<<<2048, 256, 0, stream>>>(
        x, src, dst, Ws0, Wn0, Ws1, Wn1, Ws2, Wn2,
        Whi0, Wlo0, Whi1, Wlo1, Whi2, Wlo2, hb_a, cnt, ssrc);

    // ---- fused layers (3 dispatches, 128-thread blocks) ----
    sage_layer_kernel<8, true, false><<<NTILES, 128, 0, stream>>>(
        hb_a, cnt, ssrc, Whi0, Wlo0, b0, nullptr, hb_b);
    sage_layer_kernel<8, true, false><<<NTILES, 128, 0, stream>>>(
        hb_b, cnt, ssrc, Whi1, Wlo1, b1, nullptr, hb_a);
    sage_layer_kernel<4, false, true><<<NTILES, 128, 0, stream>>>(
        hb_a, cnt, ssrc, Whi2, Wlo2, b2, out, nullptr);
}

// Round 11
// 219.489 us; speedup vs baseline: 1.2849x; 1.2849x over previous
//
#include <hip/hip_runtime.h>

#define N_NODES 50000
#define N_EDGES 600000
#define DFEAT   128
#define NTILES  ((N_NODES + 31) / 32)      // 1563 tiles of 32 rows
#define DEGCAP  64                         // max degree slots (Poisson(12) max ~35)

typedef __attribute__((ext_vector_type(8))) short short8;
typedef __attribute__((ext_vector_type(4))) float floatx4;

__device__ __forceinline__ unsigned short f2bf_rtne(float f) {
    unsigned b = __float_as_uint(f);
    return (unsigned short)((b + 0x7FFFu + ((b >> 16) & 1u)) >> 16);
}
__device__ __forceinline__ float bf2f(unsigned short u) {
    return __uint_as_float(((unsigned)u) << 16);
}
// LDS index swizzle: 32 rows x 256 ushorts (16KB). XOR bits 3..5 of col with
// row&7: all accesses are >=4-ushort aligned and stay inside one 8-ushort
// block, so write/read mappings agree. Validated R5/R7 (absmax 0.015625).
__device__ __forceinline__ int ldsx(int row, int col) {
    return row * 256 + (col ^ ((row & 7) << 3));
}

// ========== fused build: bucket-fill (cnt pre-zeroed by memset) + prep =========
__global__ __launch_bounds__(256) void sage_build_kernel(
        const float* __restrict__ x, const int* __restrict__ src, const int* __restrict__ dst,
        const float* __restrict__ Ws0, const float* __restrict__ Wn0,
        const float* __restrict__ Ws1, const float* __restrict__ Wn1,
        const float* __restrict__ Ws2, const float* __restrict__ Wn2,
        unsigned short* __restrict__ Whi0, unsigned short* __restrict__ Wlo0,
        unsigned short* __restrict__ Whi1, unsigned short* __restrict__ Wlo1,
        unsigned short* __restrict__ Whi2, unsigned short* __restrict__ Wlo2,
        unsigned short* __restrict__ hb, int* __restrict__ cnt,
        unsigned short* __restrict__ ssrc)
{
    const int gtid = blockIdx.x * 256 + threadIdx.x;
    const int gsz  = gridDim.x * 256;

    // ---- bucket fill (latency/atomic-bound; overlaps prep's streaming) ----
    for (int e = gtid; e < N_EDGES; e += gsz) {
        int d = dst[e];
        int p = atomicAdd(&cnt[d], 1);
        if (p < DEGCAP) ssrc[(d << 6) + p] = (unsigned short)src[e];
    }

    // ---- x -> bf16 table ----
    for (int i = gtid; i < N_NODES * DFEAT / 4; i += gsz) {
        float4 v = ((const float4*)x)[i];
        ushort4 o;
        o.x = f2bf_rtne(v.x); o.y = f2bf_rtne(v.y);
        o.z = f2bf_rtne(v.z); o.w = f2bf_rtne(v.w);
        ((ushort4*)hb)[i] = o;
    }

    // ---- W split/swizzle into MFMA fragment order ----
    for (int it = gtid; it < 160 * 64; it += gsz) {
        int fid_g = it >> 6;
        int lane  = it & 63;
        const float *Ws, *Wn;
        unsigned short *Whi, *Wlo;
        int N, fid;
        if (fid_g < 64)       { Ws = Ws0; Wn = Wn0; Whi = Whi0; Wlo = Wlo0; N = 128; fid = fid_g; }
        else if (fid_g < 128) { Ws = Ws1; Wn = Wn1; Whi = Whi1; Wlo = Wlo1; N = 128; fid = fid_g - 64; }
        else                  { Ws = Ws2; Wn = Wn2; Whi = Whi2; Wlo = Wlo2; N = 64;  fid = fid_g - 128; }
        int NT = N / 16;
        int kt = fid / NT, nt = fid % NT;
        int kbase = kt * 32 + (lane >> 4) * 8;
        int n = nt * 16 + (lane & 15);
        long base = ((long)fid * 64 + lane) * 8;
        #pragma unroll
        for (int j = 0; j < 8; j++) {
            int k = kbase + j;
            float w = (k < 128) ? Ws[k * N + n] : Wn[(k - 128) * N + n];
            unsigned bb = __float_as_uint(w);
            unsigned hib = bb & 0xFFFF0000u;
            float lo = w - __uint_as_float(hib);
            Whi[base + j] = (unsigned short)(bb >> 16);
            Wlo[base + j] = (unsigned short)(__float_as_uint(lo) >> 16);
        }
    }
}

// ================= FUSED layer: gather-mean + dual bf16 MFMA matmul =============
// Block = 256 threads (4 waves) owns 32 output rows (R6-proven shape).
// Phase A1: stage 32 self rows into LDS (coalesced 16B chunks) + NEW: each
//           wave stages its 8 nodes' edge-id buckets (512 ushorts = 1KB, one
//           coalesced 16B/lane load) and 8 degrees into LDS.
// Phase A2: gather (R6-proven paired-edge loop) but ids/degrees now come from
//           LDS (~60cy broadcast) instead of L2 (~200-300cy) — removes the
//           first link of the per-iteration serial latency chain.
// Phase B:  4 waves split N columns; A-frags from LDS (XOR-swizzled),
//           B-frags (hi/lo split W) from L2.
template<int NT, bool RELU, bool FINAL>
__global__ __launch_bounds__(256) void sage_layer_kernel(
        const unsigned short* __restrict__ hb, const int* __restrict__ cnt,
        const unsigned short* __restrict__ ssrc,
        const unsigned short* __restrict__ Whi, const unsigned short* __restrict__ Wlo,
        const float* __restrict__ bias, float* __restrict__ out,
        unsigned short* __restrict__ hb_out, int M)
{
    constexpr int N   = NT * 16;
    constexpr int NTW = NT / 4;          // n-tiles per wave
    __shared__ __align__(16) unsigned short lds[32 * 256];   // 16 KB feature tile
    __shared__ __align__(16) unsigned short ids[4 * 512];    // 4 KB edge-id buckets
    __shared__ int degs[32];

    const int tid  = threadIdx.x;
    const int w    = tid >> 6;
    const int lane = tid & 63;
    const int rowbase = blockIdx.x * 32;

    // ---- phase A1a: stage this wave's edge ids + degrees (wave-local) ----
    {
        // nodes rowbase+w*8 .. +7 occupy 512 contiguous ushorts in ssrc
        const unsigned short* sp = ssrc + (((long)(rowbase + w * 8)) << 6);
        *(short8*)(&ids[w * 512 + lane * 8]) = *(const short8*)(sp + lane * 8);
        if (lane < 8) {
            int node = rowbase + w * 8 + lane;
            degs[w * 8 + lane] = (node < M) ? cnt[node] : 0;
        }
    }

    // ---- phase A1b: stage self rows (coalesced 16B chunks) ----
    #pragma unroll
    for (int i = 0; i < 2; i++) {
        int idx = tid + i * 256;               // 0..511 chunks of 16B
        int r = idx >> 4, o = idx & 15;
        if (rowbase + r < M) {
            short8 v = *(const short8*)(hb + (((long)(rowbase + r)) << 7) + o * 8);
            *(short8*)(&lds[ldsx(r, o * 8)]) = v;
        }
    }

    // ---- phase A2: gather means (paired-edge, ids/degs from LDS) ----
    const int half = lane >> 5;
    const int fq   = lane & 31;                // feature quad: feats fq*4..+3
    for (int n = 0; n < 8; n++) {
        const int node = rowbase + w * 8 + n;  // wave-uniform
        if (node >= M) break;
        const int deg  = degs[w * 8 + n];      // LDS broadcast (wave-local)
        const int degc = deg < DEGCAP ? deg : DEGCAP;
        const int idb  = w * 512 + n * 64;     // this node's id bucket in LDS
        float4 s0 = make_float4(0.f, 0.f, 0.f, 0.f);
        float4 s1 = make_float4(0.f, 0.f, 0.f, 0.f);
        int e = half;
        for (; e + 2 < degc; e += 4) {
            int sA = ids[idb + e];             // LDS ~60cy vs L2 ~200-300cy
            int sB = ids[idb + e + 2];
            ushort4 vA = *(const ushort4*)(hb + ((long)sA << 7) + fq * 4);
            ushort4 vB = *(const ushort4*)(hb + ((long)sB << 7) + fq * 4);
            s0.x += bf2f(vA.x); s0.y += bf2f(vA.y); s0.z += bf2f(vA.z); s0.w += bf2f(vA.w);
            s1.x += bf2f(vB.x); s1.y += bf2f(vB.y); s1.z += bf2f(vB.z); s1.w += bf2f(vB.w);
        }
        for (; e < degc; e += 2) {
            int sA = ids[idb + e];
            ushort4 vA = *(const ushort4*)(hb + ((long)sA << 7) + fq * 4);
            s0.x += bf2f(vA.x); s0.y += bf2f(vA.y); s0.z += bf2f(vA.z); s0.w += bf2f(vA.w);
        }
        float sx = s0.x + s1.x, sy = s0.y + s1.y, sz = s0.z + s1.z, sw = s0.w + s1.w;
        sx += __shfl_down(sx, 32);
        sy += __shfl_down(sy, 32);
        sz += __shfl_down(sz, 32);
        sw += __shfl_down(sw, 32);
        if (half == 0) {
            float sc = 1.0f / fmaxf((float)deg, 1.0f);
            ushort4 r;
            r.x = f2bf_rtne(sx * sc); r.y = f2bf_rtne(sy * sc);
            r.z = f2bf_rtne(sz * sc); r.w = f2bf_rtne(sw * sc);
            *(ushort4*)(&lds[ldsx(w * 8 + n, 128 + fq * 4)]) = r;
        }
    }
    __syncthreads();

    // ---- phase B: dual matmul (self kt 0..3 | mean kt 4..7) ----
    const int q   = lane >> 4;
    const int l16 = lane & 15;

    floatx4 acc[2][NTW];
    #pragma unroll
    for (int mt = 0; mt < 2; mt++)
        #pragma unroll
        for (int ntl = 0; ntl < NTW; ntl++)
            acc[mt][ntl] = (floatx4){0.f, 0.f, 0.f, 0.f};

    int rl0 = l16;      if (rowbase + rl0 >= M) rl0 = M - 1 - rowbase;
    int rl1 = 16 + l16; if (rowbase + rl1 >= M) rl1 = M - 1 - rowbase;
    const int rl[2] = {rl0, rl1};

    #pragma unroll
    for (int kt = 0; kt < 8; kt++) {
        short8 am[2];
        #pragma unroll
        for (int mt = 0; mt < 2; mt++)
            am[mt] = *(const short8*)(&lds[ldsx(rl[mt], kt * 32 + q * 8)]);
        #pragma unroll
        for (int ntl = 0; ntl < NTW; ntl++) {
            int nt = w * NTW + ntl;
            long fb = ((long)(kt * NT + nt) * 64 + lane) * 8;
            short8 bhi = *(const short8*)(Whi + fb);
            short8 blo = *(const short8*)(Wlo + fb);
            #pragma unroll
            for (int mt = 0; mt < 2; mt++) {
                acc[mt][ntl] = __builtin_amdgcn_mfma_f32_16x16x32_bf16(am[mt], bhi, acc[mt][ntl], 0, 0, 0);
                acc[mt][ntl] = __builtin_amdgcn_mfma_f32_16x16x32_bf16(am[mt], blo, acc[mt][ntl], 0, 0, 0);
            }
        }
    }

    #pragma unroll
    for (int ntl = 0; ntl < NTW; ntl++) {
        int col = (w * NTW + ntl) * 16 + l16;
        float bv = bias[col];
        #pragma unroll
        for (int mt = 0; mt < 2; mt++) {
            #pragma unroll
            for (int reg = 0; reg < 4; reg++) {
                int grow = rowbase + mt * 16 + q * 4 + reg;
                if (grow < M) {
                    float v = acc[mt][ntl][reg] + bv;
                    if (RELU) v = fmaxf(v, 0.f);
                    long idx = (long)grow * N + col;
                    if (FINAL) out[idx] = v;
                    else       hb_out[idx] = f2bf_rtne(v);
                }
            }
        }
    }
}

extern "C" void kernel_launch(void* const* d_in, const int* in_sizes, int n_in,
                              void* d_out, int out_size, void* d_ws, size_t ws_size,
                              hipStream_t stream) {
    const float* x   = (const float*)d_in[0];
    const int*   ei  = (const int*)d_in[1];
    const float* Ws0 = (const float*)d_in[2];
    const float* Wn0 = (const float*)d_in[3];
    const float* b0  = (const float*)d_in[4];
    const float* Ws1 = (const float*)d_in[5];
    const float* Wn1 = (const float*)d_in[6];
    const float* b1  = (const float*)d_in[7];
    const float* Ws2 = (const float*)d_in[8];
    const float* Wn2 = (const float*)d_in[9];
    const float* b2  = (const float*)d_in[10];
    float* out = (float*)d_out;

    const int* src = ei;
    const int* dst = ei + N_EDGES;

    // ---- workspace layout ----
    char* ws = (char*)d_ws;
    int*   cnt        = (int*)ws;     ws += 50176 * 4;
    unsigned short* ssrc = (unsigned short*)ws; ws += (long)N_NODES * DEGCAP * 2; // 6.4 MB
    unsigned short* Whi0 = (unsigned short*)ws; ws += 8 * 8 * 64 * 8 * 2;   // 64 KB
    unsigned short* Wlo0 = (unsigned short*)ws; ws += 8 * 8 * 64 * 8 * 2;
    unsigned short* Whi1 = (unsigned short*)ws; ws += 8 * 8 * 64 * 8 * 2;
    unsigned short* Wlo1 = (unsigned short*)ws; ws += 8 * 8 * 64 * 8 * 2;
    unsigned short* Whi2 = (unsigned short*)ws; ws += 8 * 4 * 64 * 8 * 2;   // 32 KB
    unsigned short* Wlo2 = (unsigned short*)ws; ws += 8 * 4 * 64 * 8 * 2;
    unsigned short* hb_a = (unsigned short*)ws; ws += (long)N_NODES * DFEAT * 2; // 12.8 MB
    unsigned short* hb_b = (unsigned short*)ws; ws += (long)N_NODES * DFEAT * 2; // 12.8 MB

    // ---- build: memset(cnt) + fused fill/prep (2 enqueues) ----
    hipMemsetAsync(cnt, 0, 50176 * 4, stream);
    sage_build_kernel<<<2048, 256, 0, stream>>>(
        x, src, dst, Ws0, Wn0, Ws1, Wn1, Ws2, Wn2,
        Whi0, Wlo0, Whi1, Wlo1, Whi2, Wlo2, hb_a, cnt, ssrc);

    // ---- fused layers (3 dispatches) ----
    sage_layer_kernel<8, true, false><<<NTILES, 256, 0, stream>>>(
        hb_a, cnt, ssrc, Whi0, Wlo0, b0, nullptr, hb_b, N_NODES);
    sage_layer_kernel<8, true, false><<<NTILES, 256, 0, stream>>>(
        hb_b, cnt, ssrc, Whi1, Wlo1, b1, nullptr, hb_a, N_NODES);
    sage_layer_kernel<4, false, true><<<NTILES, 256, 0, stream>>>(
        hb_a, cnt, ssrc, Whi2, Wlo2, b2, out, nullptr, N_NODES);
}

// Round 12
// 211.734 us; speedup vs baseline: 1.3320x; 1.0366x over previous
//
#include <hip/hip_runtime.h>

#define N_NODES 50000
#define N_EDGES 600000
#define DFEAT   128
#define NTILES  ((N_NODES + 31) / 32)      // 1563 tiles of 32 rows
#define DEGCAP  64                         // max degree slots (Poisson(12) max ~35)
#define NCLS    8                          // XCD classes
#define NPC     (N_NODES / NCLS)           // 6250 nodes per class

typedef __attribute__((ext_vector_type(8))) short short8;
typedef __attribute__((ext_vector_type(4))) float floatx4;

__device__ __forceinline__ unsigned short f2bf_rtne(float f) {
    unsigned b = __float_as_uint(f);
    return (unsigned short)((b + 0x7FFFu + ((b >> 16) & 1u)) >> 16);
}
__device__ __forceinline__ float bf2f(unsigned short u) {
    return __uint_as_float(((unsigned)u) << 16);
}
// LDS index swizzle: 32 rows x 256 ushorts (16KB). XOR bits 3..5 of col with
// row&7: all accesses are >=4-ushort aligned and stay inside one 8-ushort
// block, so write/read mappings agree. Validated R5/R7 (absmax 0.015625).
__device__ __forceinline__ int ldsx(int row, int col) {
    return row * 256 + (col ^ ((row & 7) << 3));
}

// ========== fused build: XCD-partitioned bucket-fill + prep ====================
// Bucket fill is partitioned by destination-node range: class c = blockIdx&7
// (matches the round-robin blockIdx->XCD mapping; partition is correctness-
// neutral) owns nodes [c*6250,(c+1)*6250). All atomics/stores for a bucket
// come from ONE XCD -> its L2 owns the cnt/ssrc lines exclusively (no cross-
// XCD partial-line writeback ping-pong). Each class scans the whole edge
// list (dst re-read 8x total, L3-served).
__global__ __launch_bounds__(256) void sage_build_kernel(
        const float* __restrict__ x, const int* __restrict__ src, const int* __restrict__ dst,
        const float* __restrict__ Ws0, const float* __restrict__ Wn0,
        const float* __restrict__ Ws1, const float* __restrict__ Wn1,
        const float* __restrict__ Ws2, const float* __restrict__ Wn2,
        unsigned short* __restrict__ Whi0, unsigned short* __restrict__ Wlo0,
        unsigned short* __restrict__ Whi1, unsigned short* __restrict__ Wlo1,
        unsigned short* __restrict__ Whi2, unsigned short* __restrict__ Wlo2,
        unsigned short* __restrict__ hb, int* __restrict__ cnt,
        unsigned short* __restrict__ ssrc)
{
    const int gtid = blockIdx.x * 256 + threadIdx.x;
    const int gsz  = gridDim.x * 256;

    // ---- bucket fill, XCD-partitioned by dst range ----
    {
        const int cls  = blockIdx.x & (NCLS - 1);          // XCD class
        const int cblk = blockIdx.x >> 3;                  // block idx in class
        const int nlo  = cls * NPC, nhi = nlo + NPC;
        const int ct   = cblk * 256 + threadIdx.x;         // 0..65535
        const int cstr = (gridDim.x >> 3) * 256;           // 65536
        for (int e = ct; e < N_EDGES; e += cstr) {
            int d = dst[e];
            if (d >= nlo && d < nhi) {
                int p = atomicAdd(&cnt[d], 1);
                if (p < DEGCAP) ssrc[(d << 6) + p] = (unsigned short)src[e];
            }
        }
    }

    // ---- x -> bf16 table ----
    for (int i = gtid; i < N_NODES * DFEAT / 4; i += gsz) {
        float4 v = ((const float4*)x)[i];
        ushort4 o;
        o.x = f2bf_rtne(v.x); o.y = f2bf_rtne(v.y);
        o.z = f2bf_rtne(v.z); o.w = f2bf_rtne(v.w);
        ((ushort4*)hb)[i] = o;
    }

    // ---- W split/swizzle into MFMA fragment order ----
    for (int it = gtid; it < 160 * 64; it += gsz) {
        int fid_g = it >> 6;
        int lane  = it & 63;
        const float *Ws, *Wn;
        unsigned short *Whi, *Wlo;
        int N, fid;
        if (fid_g < 64)       { Ws = Ws0; Wn = Wn0; Whi = Whi0; Wlo = Wlo0; N = 128; fid = fid_g; }
        else if (fid_g < 128) { Ws = Ws1; Wn = Wn1; Whi = Whi1; Wlo = Wlo1; N = 128; fid = fid_g - 64; }
        else                  { Ws = Ws2; Wn = Wn2; Whi = Whi2; Wlo = Wlo2; N = 64;  fid = fid_g - 128; }
        int NT = N / 16;
        int kt = fid / NT, nt = fid % NT;
        int kbase = kt * 32 + (lane >> 4) * 8;
        int n = nt * 16 + (lane & 15);
        long base = ((long)fid * 64 + lane) * 8;
        #pragma unroll
        for (int j = 0; j < 8; j++) {
            int k = kbase + j;
            float w = (k < 128) ? Ws[k * N + n] : Wn[(k - 128) * N + n];
            unsigned bb = __float_as_uint(w);
            unsigned hib = bb & 0xFFFF0000u;
            float lo = w - __uint_as_float(hib);
            Whi[base + j] = (unsigned short)(bb >> 16);
            Wlo[base + j] = (unsigned short)(__float_as_uint(lo) >> 16);
        }
    }
}

// ================= FUSED layer: gather-mean + dual bf16 MFMA matmul =============
// (unchanged from R11: 4 waves/32 rows, LDS-staged edge ids + degrees,
//  paired-edge gather, XOR-swizzled LDS, dual MFMA)
template<int NT, bool RELU, bool FINAL>
__global__ __launch_bounds__(256) void sage_layer_kernel(
        const unsigned short* __restrict__ hb, const int* __restrict__ cnt,
        const unsigned short* __restrict__ ssrc,
        const unsigned short* __restrict__ Whi, const unsigned short* __restrict__ Wlo,
        const float* __restrict__ bias, float* __restrict__ out,
        unsigned short* __restrict__ hb_out, int M)
{
    constexpr int N   = NT * 16;
    constexpr int NTW = NT / 4;          // n-tiles per wave
    __shared__ __align__(16) unsigned short lds[32 * 256];   // 16 KB feature tile
    __shared__ __align__(16) unsigned short ids[4 * 512];    // 4 KB edge-id buckets
    __shared__ int degs[32];

    const int tid  = threadIdx.x;
    const int w    = tid >> 6;
    const int lane = tid & 63;
    const int rowbase = blockIdx.x * 32;

    // ---- phase A1a: stage this wave's edge ids + degrees (wave-local) ----
    {
        const unsigned short* sp = ssrc + (((long)(rowbase + w * 8)) << 6);
        *(short8*)(&ids[w * 512 + lane * 8]) = *(const short8*)(sp + lane * 8);
        if (lane < 8) {
            int node = rowbase + w * 8 + lane;
            degs[w * 8 + lane] = (node < M) ? cnt[node] : 0;
        }
    }

    // ---- phase A1b: stage self rows (coalesced 16B chunks) ----
    #pragma unroll
    for (int i = 0; i < 2; i++) {
        int idx = tid + i * 256;               // 0..511 chunks of 16B
        int r = idx >> 4, o = idx & 15;
        if (rowbase + r < M) {
            short8 v = *(const short8*)(hb + (((long)(rowbase + r)) << 7) + o * 8);
            *(short8*)(&lds[ldsx(r, o * 8)]) = v;
        }
    }

    // ---- phase A2: gather means (paired-edge, ids/degs from LDS) ----
    const int half = lane >> 5;
    const int fq   = lane & 31;                // feature quad: feats fq*4..+3
    for (int n = 0; n < 8; n++) {
        const int node = rowbase + w * 8 + n;  // wave-uniform
        if (node >= M) break;
        const int deg  = degs[w * 8 + n];      // LDS broadcast (wave-local)
        const int degc = deg < DEGCAP ? deg : DEGCAP;
        const int idb  = w * 512 + n * 64;     // this node's id bucket in LDS
        float4 s0 = make_float4(0.f, 0.f, 0.f, 0.f);
        float4 s1 = make_float4(0.f, 0.f, 0.f, 0.f);
        int e = half;
        for (; e + 2 < degc; e += 4) {
            int sA = ids[idb + e];             // LDS ~60cy vs L2 ~200-300cy
            int sB = ids[idb + e + 2];
            ushort4 vA = *(const ushort4*)(hb + ((long)sA << 7) + fq * 4);
            ushort4 vB = *(const ushort4*)(hb + ((long)sB << 7) + fq * 4);
            s0.x += bf2f(vA.x); s0.y += bf2f(vA.y); s0.z += bf2f(vA.z); s0.w += bf2f(vA.w);
            s1.x += bf2f(vB.x); s1.y += bf2f(vB.y); s1.z += bf2f(vB.z); s1.w += bf2f(vB.w);
        }
        for (; e < degc; e += 2) {
            int sA = ids[idb + e];
            ushort4 vA = *(const ushort4*)(hb + ((long)sA << 7) + fq * 4);
            s0.x += bf2f(vA.x); s0.y += bf2f(vA.y); s0.z += bf2f(vA.z); s0.w += bf2f(vA.w);
        }
        float sx = s0.x + s1.x, sy = s0.y + s1.y, sz = s0.z + s1.z, sw = s0.w + s1.w;
        sx += __shfl_down(sx, 32);
        sy += __shfl_down(sy, 32);
        sz += __shfl_down(sz, 32);
        sw += __shfl_down(sw, 32);
        if (half == 0) {
            float sc = 1.0f / fmaxf((float)deg, 1.0f);
            ushort4 r;
            r.x = f2bf_rtne(sx * sc); r.y = f2bf_rtne(sy * sc);
            r.z = f2bf_rtne(sz * sc); r.w = f2bf_rtne(sw * sc);
            *(ushort4*)(&lds[ldsx(w * 8 + n, 128 + fq * 4)]) = r;
        }
    }
    __syncthreads();

    // ---- phase B: dual matmul (self kt 0..3 | mean kt 4..7) ----
    const int q   = lane >> 4;
    const int l16 = lane & 15;

    floatx4 acc[2][NTW];
    #pragma unroll
    for (int mt = 0; mt < 2; mt++)
        #pragma unroll
        for (int ntl = 0; ntl < NTW; ntl++)
            acc[mt][ntl] = (floatx4){0.f, 0.f, 0.f, 0.f};

    int rl0 = l16;      if (rowbase + rl0 >= M) rl0 = M - 1 - rowbase;
    int rl1 = 16 + l16; if (rowbase + rl1 >= M) rl1 = M - 1 - rowbase;
    const int rl[2] = {rl0, rl1};

    #pragma unroll
    for (int kt = 0; kt < 8; kt++) {
        short8 am[2];
        #pragma unroll
        for (int mt = 0; mt < 2; mt++)
            am[mt] = *(const short8*)(&lds[ldsx(rl[mt], kt * 32 + q * 8)]);
        #pragma unroll
        for (int ntl = 0; ntl < NTW; ntl++) {
            int nt = w * NTW + ntl;
            long fb = ((long)(kt * NT + nt) * 64 + lane) * 8;
            short8 bhi = *(const short8*)(Whi + fb);
            short8 blo = *(const short8*)(Wlo + fb);
            #pragma unroll
            for (int mt = 0; mt < 2; mt++) {
                acc[mt][ntl] = __builtin_amdgcn_mfma_f32_16x16x32_bf16(am[mt], bhi, acc[mt][ntl], 0, 0, 0);
                acc[mt][ntl] = __builtin_amdgcn_mfma_f32_16x16x32_bf16(am[mt], blo, acc[mt][ntl], 0, 0, 0);
            }
        }
    }

    #pragma unroll
    for (int ntl = 0; ntl < NTW; ntl++) {
        int col = (w * NTW + ntl) * 16 + l16;
        float bv = bias[col];
        #pragma unroll
        for (int mt = 0; mt < 2; mt++) {
            #pragma unroll
            for (int reg = 0; reg < 4; reg++) {
                int grow = rowbase + mt * 16 + q * 4 + reg;
                if (grow < M) {
                    float v = acc[mt][ntl][reg] + bv;
                    if (RELU) v = fmaxf(v, 0.f);
                    long idx = (long)grow * N + col;
                    if (FINAL) out[idx] = v;
                    else       hb_out[idx] = f2bf_rtne(v);
                }
            }
        }
    }
}

extern "C" void kernel_launch(void* const* d_in, const int* in_sizes, int n_in,
                              void* d_out, int out_size, void* d_ws, size_t ws_size,
                              hipStream_t stream) {
    const float* x   = (const float*)d_in[0];
    const int*   ei  = (const int*)d_in[1];
    const float* Ws0 = (const float*)d_in[2];
    const float* Wn0 = (const float*)d_in[3];
    const float* b0  = (const float*)d_in[4];
    const float* Ws1 = (const float*)d_in[5];
    const float* Wn1 = (const float*)d_in[6];
    const float* b1  = (const float*)d_in[7];
    const float* Ws2 = (const float*)d_in[8];
    const float* Wn2 = (const float*)d_in[9];
    const float* b2  = (const float*)d_in[10];
    float* out = (float*)d_out;

    const int* src = ei;
    const int* dst = ei + N_EDGES;

    // ---- workspace layout ----
    char* ws = (char*)d_ws;
    int*   cnt        = (int*)ws;     ws += 50176 * 4;
    unsigned short* ssrc = (unsigned short*)ws; ws += (long)N_NODES * DEGCAP * 2; // 6.4 MB
    unsigned short* Whi0 = (unsigned short*)ws; ws += 8 * 8 * 64 * 8 * 2;   // 64 KB
    unsigned short* Wlo0 = (unsigned short*)ws; ws += 8 * 8 * 64 * 8 * 2;
    unsigned short* Whi1 = (unsigned short*)ws; ws += 8 * 8 * 64 * 8 * 2;
    unsigned short* Wlo1 = (unsigned short*)ws; ws += 8 * 8 * 64 * 8 * 2;
    unsigned short* Whi2 = (unsigned short*)ws; ws += 8 * 4 * 64 * 8 * 2;   // 32 KB
    unsigned short* Wlo2 = (unsigned short*)ws; ws += 8 * 4 * 64 * 8 * 2;
    unsigned short* hb_a = (unsigned short*)ws; ws += (long)N_NODES * DFEAT * 2; // 12.8 MB
    unsigned short* hb_b = (unsigned short*)ws; ws += (long)N_NODES * DFEAT * 2; // 12.8 MB

    // ---- build: memset(cnt) + fused fill/prep (2 enqueues) ----
    hipMemsetAsync(cnt, 0, 50176 * 4, stream);
    sage_build_kernel<<<2048, 256, 0, stream>>>(
        x, src, dst, Ws0, Wn0, Ws1, Wn1, Ws2, Wn2,
        Whi0, Wlo0, Whi1, Wlo1, Whi2, Wlo2, hb_a, cnt, ssrc);

    // ---- fused layers (3 dispatches) ----
    sage_layer_kernel<8, true, false><<<NTILES, 256, 0, stream>>>(
        hb_a, cnt, ssrc, Whi0, Wlo0, b0, nullptr, hb_b, N_NODES);
    sage_layer_kernel<8, true, false><<<NTILES, 256, 0, stream>>>(
        hb_b, cnt, ssrc, Whi1, Wlo1, b1, nullptr, hb_a, N_NODES);
    sage_layer_kernel<4, false, true><<<NTILES, 256, 0, stream>>>(
        hb_a, cnt, ssrc, Whi2, Wlo2, b2, out, nullptr, N_NODES);
}